// Round 8
// baseline (115956.689 us; speedup 1.0000x reference)
//
#include <hip/hip_runtime.h>
#include <hip/hip_fp16.h>
#include <math.h>

// ---------------------------------------------------------------------------
// FARGAN core. B=128, T=504, nb_frames=500, steps=2000, SUB=40.
// Round 8: phase restructure. In-wave shuffle reductions (1 phase per matvec),
// GRU/skip inputs read in place with compile-time segment bounds (pg scaling
// folded into a second accumulator), ring-buffer exc. 15 barriers/step vs 24.
// Streaming weight plan identical to round 6 (LDS stash fwcglu+glu2+glu3).
// ---------------------------------------------------------------------------

#define DEV __device__ __forceinline__

DEV float sigm(float x) { return 1.0f / (1.0f + __expf(-x)); }
DEV float tanh_f(float x) { return 1.0f - 2.0f / (__expf(2.0f * x) + 1.0f); }

typedef _Float16 h2v __attribute__((ext_vector_type(2)));

#if defined(__has_builtin)
#if __has_builtin(__builtin_amdgcn_fdot2)
#define HAVE_FDOT2 1
#endif
#endif

DEV float fdot2(h2v a, h2v b, float c) {
#ifdef HAVE_FDOT2
    return __builtin_amdgcn_fdot2(a, b, c, false);
#else
    return c + (float)a[0] * (float)b[0] + (float)a[1] * (float)b[1];
#endif
}

// ---- workspace layout (float offsets) ----
constexpr size_t STEPS = 2000;
constexpr size_t OFF_X     = 0;          // 128*502*64 f32
constexpr size_t OFF_Y     = 4200000;    // 128*500*128 f32
constexpr size_t OFF_GAIN  = 12392000;   // 128*2000 f32
constexpr size_t OFF_CONDH = 12648000;   // 128*500*320 halves
constexpr size_t OFF_W     = 22888000;   // fp16 weights

// packed fp16 weights: OUT*KPAD halves, layout uint4[(k/8)*OUT + j]
constexpr size_t W_FWC     = 0;                       // 192 x 352
constexpr size_t W_FWCGLU  = W_FWC    + 192*352;      // 192 x 192  (LDS)
constexpr size_t W_GOUT    = W_FWCGLU + 192*192;      // 4   x 192
constexpr size_t W_G1IH    = W_GOUT   + 4*192;        // 480 x 272
constexpr size_t W_G1HH    = W_G1IH   + 480*272;      // 480 x 160
constexpr size_t W_GLU1    = W_G1HH   + 480*160;      // 160 x 160
constexpr size_t W_G2IH    = W_GLU1   + 160*160;      // 384 x 240
constexpr size_t W_G2HH    = W_G2IH   + 384*240;      // 384 x 128
constexpr size_t W_GLU2    = W_G2HH   + 384*128;      // 128 x 128  (LDS)
constexpr size_t W_G3IH    = W_GLU2   + 128*128;      // 384 x 208
constexpr size_t W_G3HH    = W_G3IH   + 384*208;      // 384 x 128
constexpr size_t W_GLU3    = W_G3HH   + 384*128;      // 128 x 128  (LDS)
constexpr size_t W_SKIP    = W_GLU3   + 128*128;      // 128 x 704
constexpr size_t W_SKIPGLU = W_SKIP   + 128*704;      // 128 x 128
constexpr size_t W_SIG     = W_SKIPGLU+ 128*128;      // 40  x 128

// LDS weight stash (uint4 units), +1 uint4 pad per slice to break bank aliasing
// fwcglu: LS=4, slice=6*192=1152 -> stride 1153; glu2/3: LS=8, slice=2*128=256 -> 257
constexpr int WL_FWCGLU = 0;                  // 4*1153 = 4612
constexpr int WL_GLU2   = 4612;               // 8*257  = 2056
constexpr int WL_GLU3   = 4612 + 2056;        // 8*257  = 2056
constexpr int WL_TOT    = 4612 + 2056 + 2056; // 8724 uint4 = 139,584 B

// ---------------------------------------------------------------------------
__global__ void k_pack_h(const float* __restrict__ src, __half* __restrict__ dst,
                         int OUT, int K, int KP8) {
    int t = blockIdx.x * 256 + threadIdx.x;
    if (t >= OUT * KP8) return;
    int j = t % OUT;
    int k8 = t / OUT;
    __half* d = dst + (size_t)t * 8;
#pragma unroll
    for (int i = 0; i < 8; ++i) {
        int k = k8 * 8 + i;
        d[i] = (k < K) ? __float2half(src[(size_t)j * K + k]) : __float2half(0.0f);
    }
}

// ---------------------------------------------------------------------------
// frontend (unchanged — verified)
// ---------------------------------------------------------------------------
__global__ void k_feat(const float* __restrict__ features, const int* __restrict__ period,
                       const float* __restrict__ pembed, const float* __restrict__ fd1,
                       float* __restrict__ xbuf) {
    int t = blockIdx.x * 256 + threadIdx.x;
    const int total = 128 * 502 * 64;
    if (t >= total) return;
    int o = t & 63;
    int r = t >> 6;
    int ft = r % 502;
    int b = r / 502;
    const float* f = features + ((size_t)b * 504 + ft + 2) * 20;
    int per = period[b * 504 + ft + 2];
    per = min(max(per, 32), 254);
    const float* pe = pembed + (per - 32) * 12;
    const float* w = fd1 + o * 32;
    float acc = 0.0f;
#pragma unroll
    for (int i = 0; i < 20; ++i) acc += f[i] * w[i];
#pragma unroll
    for (int i = 0; i < 12; ++i) acc += pe[i] * w[20 + i];
    xbuf[t] = tanh_f(acc);
}

__global__ void k_conv(const float* __restrict__ xbuf, const float* __restrict__ fconv1,
                       float* __restrict__ ybuf) {
    int t = blockIdx.x * 256 + threadIdx.x;
    const int total = 128 * 500 * 128;
    if (t >= total) return;
    int oc = t & 127;
    int r = t >> 7;
    int tt = r % 500;
    int b = r / 500;
    const float* xp = xbuf + ((size_t)b * 502 + tt) * 64;
    const float* w = fconv1 + oc * 192;
    float acc = 0.0f;
#pragma unroll 8
    for (int i = 0; i < 64; ++i) {
        acc += xp[i] * w[i * 3 + 0];
        acc += xp[64 + i] * w[i * 3 + 1];
        acc += xp[128 + i] * w[i * 3 + 2];
    }
    ybuf[t] = tanh_f(acc);
}

__global__ void k_cond(const float* __restrict__ ybuf, const float* __restrict__ fd2,
                       __half* __restrict__ cond) {
    int b = blockIdx.x / 50;
    int t0 = (blockIdx.x % 50) * 10;
    int tid = threadIdx.x;
    __shared__ float yl[1280];
    for (int i = tid; i < 1280; i += 320)
        yl[i] = ybuf[((size_t)b * 500 + t0) * 128 + i];
    __syncthreads();
    const float* w = fd2 + tid * 128;
    float acc[10];
#pragma unroll
    for (int q = 0; q < 10; ++q) acc[q] = 0.0f;
#pragma unroll 4
    for (int k = 0; k < 128; ++k) {
        float wv = w[k];
#pragma unroll
        for (int q = 0; q < 10; ++q) acc[q] += wv * yl[q * 128 + k];
    }
#pragma unroll
    for (int q = 0; q < 10; ++q)
        cond[((size_t)b * 500 + t0 + q) * 320 + tid] = __float2half(tanh_f(acc[q]));
}

__global__ void k_gain(const __half* __restrict__ cond, const float* __restrict__ cgw,
                       const float* __restrict__ cgb, float* __restrict__ gains) {
    int t = blockIdx.x * 256 + threadIdx.x;
    const int total = 128 * 2000;
    if (t >= total) return;
    int s = t % 2000;
    int b = t / 2000;
    int frame = s >> 2, sub = s & 3;
    const __half* c = cond + ((size_t)b * 500 + frame) * 320 + sub * 80;
    float acc = 0.0f;
#pragma unroll 8
    for (int i = 0; i < 80; ++i) acc += __half2float(c[i]) * cgw[i];
    float g = 0.2f + 0.8f * sigm(acc + cgb[0]);
    g = fminf(20.0f, fmaxf(0.001f, g));
    gains[t] = g;
}

// ---------------------------------------------------------------------------
DEV void dot8h(uint4 w, uint4 x, float& a0, float& a1) {
    const h2v* wv = (const h2v*)&w;
    const h2v* xv = (const h2v*)&x;
    a0 = fdot2(wv[0], xv[0], a0);
    a1 = fdot2(wv[1], xv[1], a1);
    a0 = fdot2(wv[2], xv[2], a0);
    a1 = fdot2(wv[3], xv[3], a1);
}

// single-source matvec, in-wave shuffle reduce. All LS lanes return full sum.
template <int OUT, int KP8, int LS>
DEV float mv_red(const uint4* __restrict__ W, const __half* __restrict__ x, int tid) {
    static_assert(KP8 % LS == 0, "KP8 % LS");
    constexpr int KS8 = KP8 / LS;
    const int j = tid / LS;
    const int sl = tid % LS;
    const uint4* w = W + (size_t)(sl * KS8) * OUT + j;
    const uint4* xx = (const uint4*)x + sl * KS8;
    float a0 = 0.0f, a1 = 0.0f;
#pragma unroll
    for (int k = 0; k < KS8; ++k) dot8h(w[(size_t)k * OUT], xx[k], a0, a1);
    float a = a0 + a1;
#pragma unroll
    for (int m = LS / 2; m >= 1; m >>= 1) a += __shfl_xor(a, m, 64);
    return a;
}

// LDS-stash matvec (padded slice stride = KS8*OUT + 1), in-wave reduce.
template <int OUT, int KP8, int LS>
DEV float mv_red_l(const uint4* wl, const __half* __restrict__ x, int tid) {
    constexpr int KS8 = KP8 / LS;
    constexpr int STRIDE = KS8 * OUT + 1;
    const int j = tid / LS;
    const int sl = tid % LS;
    const uint4* w = wl + sl * STRIDE + j;
    const uint4* xx = (const uint4*)x + sl * KS8;
    float a0 = 0.0f, a1 = 0.0f;
#pragma unroll
    for (int k = 0; k < KS8; ++k) dot8h(w[(size_t)k * OUT], xx[k], a0, a1);
    float a = a0 + a1;
#pragma unroll
    for (int m = LS / 2; m >= 1; m >>= 1) a += __shfl_xor(a, m, 64);
    return a;
}

// GRU gi: one thread per output, segmented sources [xmain | pg*pitch | prev].
template <int OUT, int C0>
DEV float gru_gi(const uint4* __restrict__ W, const __half* __restrict__ xmain,
                 const __half* __restrict__ pitch, const __half* __restrict__ prev,
                 float pgv, int j) {
    const uint4* xm = (const uint4*)xmain;
    const uint4* xp = (const uint4*)pitch;
    const uint4* xv = (const uint4*)prev;
    float a0 = 0.0f, a1 = 0.0f, p0 = 0.0f, p1 = 0.0f;
#pragma unroll
    for (int k = 0; k < C0; ++k) dot8h(W[(size_t)k * OUT + j], xm[k], a0, a1);
#pragma unroll
    for (int k = 0; k < 5; ++k) dot8h(W[(size_t)(C0 + k) * OUT + j], xp[k], p0, p1);
#pragma unroll
    for (int k = 0; k < 5; ++k) dot8h(W[(size_t)(C0 + 5 + k) * OUT + j], xv[k], a0, a1);
    return a0 + a1 + pgv * (p0 + p1);
}

// GRU gh: one thread per output, single source.
template <int OUT, int CH>
DEV float gru_gh(const uint4* __restrict__ W, const __half* __restrict__ s, int j) {
    const uint4* xx = (const uint4*)s;
    float b0 = 0.0f, b1 = 0.0f;
#pragma unroll
    for (int k = 0; k < CH; ++k) dot8h(W[(size_t)k * OUT + j], xx[k], b0, b1);
    return b0 + b1;
}

// ---------------------------------------------------------------------------
// main recurrent kernel: 128 blocks x 1024 threads
// ---------------------------------------------------------------------------
__global__ __launch_bounds__(1024) void fargan_main(const float* __restrict__ ws,
                                                    const int* __restrict__ period,
                                                    const float* __restrict__ goutb,
                                                    float* __restrict__ out) {
    const int b = blockIdx.x;
    const int tid = threadIdx.x;

    const __half* cond = (const __half*)(ws + OFF_CONDH);
    const float* gains = ws + OFF_GAIN;
    const __half* whb  = (const __half*)(ws + OFF_W);
    const uint4* wFWC     = (const uint4*)(whb + W_FWC);
    const uint4* wFWCGLU  = (const uint4*)(whb + W_FWCGLU);
    const uint4* wGOUT    = (const uint4*)(whb + W_GOUT);
    const uint4* wG1IH    = (const uint4*)(whb + W_G1IH);
    const uint4* wG1HH    = (const uint4*)(whb + W_G1HH);
    const uint4* wGLU1    = (const uint4*)(whb + W_GLU1);
    const uint4* wG2IH    = (const uint4*)(whb + W_G2IH);
    const uint4* wG2HH    = (const uint4*)(whb + W_G2HH);
    const uint4* wGLU2    = (const uint4*)(whb + W_GLU2);
    const uint4* wG3IH    = (const uint4*)(whb + W_G3IH);
    const uint4* wG3HH    = (const uint4*)(whb + W_G3HH);
    const uint4* wGLU3    = (const uint4*)(whb + W_GLU3);
    const uint4* wSKIP    = (const uint4*)(whb + W_SKIP);
    const uint4* wSKIPGLU = (const uint4*)(whb + W_SKIPGLU);
    const uint4* wSIG     = (const uint4*)(whb + W_SIG);

    __shared__ __align__(16) uint4 wlds[WL_TOT];

    // fp16 matvec inputs (all chunk-aligned)
    __shared__ __align__(16) __half xcat_h[352];    // [state 164|cond 80|pred 44|prev 40|pad]
    __shared__ __align__(16) __half fwcpre_h[192], fwcout_h[192];
    __shared__ __align__(16) __half s1_h[160], s2_h[128], s3_h[128];
    __shared__ __align__(16) __half g1_h[160], g2_h[128];
    __shared__ __align__(16) __half skipin_h[704], skippre_h[128], skipout_h[128];
    __shared__ __align__(16) __half pitch_h[40];    // unscaled fpitch, 5 chunks
    __shared__ __align__(16) __half prev_h[56];     // prev, 5 chunks + 2 pad chunks
    // fp32 masters
    __shared__ __align__(16) float ring[256];       // exc ring buffer
    __shared__ __align__(16) float s1[160], s2[128], s3[128];
    __shared__ __align__(16) float fwcpre[192], skippre[128];
    __shared__ __align__(16) float gi_s[480], gh_s[480];
    __shared__ __align__(16) float pg[4], goutb_l[4];

    // stash LDS weights (with +1 uint4 pad per slice)
    for (int i = tid; i < 4608; i += 1024) {
        int sl = i / 1152, rem = i % 1152;
        wlds[WL_FWCGLU + sl * 1153 + rem] = wFWCGLU[i];
    }
    for (int i = tid; i < 2048; i += 1024) {
        int sl = i / 256, rem = i % 256;
        wlds[WL_GLU2 + sl * 257 + rem] = wGLU2[i];
        wlds[WL_GLU3 + sl * 257 + rem] = wGLU3[i];
    }

    // zero-init state
    for (int i = tid; i < 256; i += 1024) ring[i] = 0.0f;
    if (tid < 160) { s1[tid] = 0.0f; s1_h[tid] = __float2half(0.0f); }
    if (tid < 128) { s2[tid] = 0.0f; s3[tid] = 0.0f;
                     s2_h[tid] = __float2half(0.0f); s3_h[tid] = __float2half(0.0f); }
    if (tid < 164) xcat_h[tid] = __float2half(0.0f);
    if (tid >= 328 && tid < 352) xcat_h[tid] = __float2half(0.0f);    // fwc K-pad
    if (tid >= 688 && tid < 704) skipin_h[tid] = __float2half(0.0f);  // skip K-pad
    if (tid >= 704 && tid < 720) prev_h[tid - 704 + 40] = __float2half(0.0f); // pad
    if (tid < 4) goutb_l[tid] = goutb[tid];
    __syncthreads();

    for (int s = 0; s < (int)STEPS; ++s) {
        const int frame = s >> 2;
        const int head = (s * 40) & 255;
        const float gain = gains[(size_t)b * 2000 + s];
        const float ig = 1.0f / (1e-5f + gain);
        int per = period[b * 504 + 3 + frame];
        per = min(max(per, 32), 254);

        // ---- A: gather cond80, pred, prev into xcat_h (ring reads) ----
        if (tid < 80) {
            xcat_h[164 + tid] = cond[((size_t)b * 500 + frame) * 320 + (s & 3) * 80 + tid];
        } else if (tid >= 128 && tid < 172) {
            int j = tid - 128;
            int idx = 254 - per + j;
            if (idx >= 256) idx -= per;
            idx = min(255, max(0, idx));
            xcat_h[244 + j] = __float2half(ring[(head + idx) & 255] * ig);
        } else if (tid >= 192 && tid < 232) {
            int j = tid - 192;
            xcat_h[288 + j] = __float2half(ring[(head + 216 + j) & 255] * ig);
        }
        __syncthreads();

        // ---- B: fwc (768 thr, LS=4) || pitch/prev copy ----
        if (tid < 768) {
            float a = mv_red<192, 44, 4>(wFWC, xcat_h, tid);
            if ((tid & 3) == 0) {
                int j = tid >> 2;
                float t = tanh_f(a);
                fwcpre[j] = t;
                fwcpre_h[j] = __float2half(t);
            }
        } else if (tid < 808) {
            pitch_h[tid - 768] = xcat_h[246 + tid - 768];
        } else if (tid < 848) {
            prev_h[tid - 808] = xcat_h[288 + tid - 808];
        }
        __syncthreads();

        // ---- D: fwcglu (LDS, 768) || gout (32) || xcat shift (164) ----
        if (tid < 768) {
            float a = mv_red_l<192, 24, 4>(wlds + WL_FWCGLU, fwcpre_h, tid);
            if ((tid & 3) == 0) {
                int j = tid >> 2;
                float v = fwcpre[j] * sigm(a);
                __half vh = __float2half(v);
                fwcout_h[j] = vh;
                skipin_h[416 + j] = vh;
            }
        } else if (tid < 800) {
            int t2 = tid - 768;
            int j = t2 >> 3, sl = t2 & 7;          // OUT=4, KP8=24, LS=8, KS8=3
            const uint4* xx = (const uint4*)fwcpre_h;
            float a0 = 0.0f, a1 = 0.0f;
#pragma unroll
            for (int k = 0; k < 3; ++k) dot8h(wGOUT[(size_t)(sl * 3 + k) * 4 + j],
                                              xx[sl * 3 + k], a0, a1);
            float a = a0 + a1;
            a += __shfl_xor(a, 1, 64);
            a += __shfl_xor(a, 2, 64);
            a += __shfl_xor(a, 4, 64);
            if (sl == 0) pg[j] = sigm(a + goutb_l[j]);
        } else if (tid >= 832 && tid < 996) {
            xcat_h[tid - 832] = xcat_h[tid - 832 + 164];
        }
        __syncthreads();

        // ---- F: GRU1 matvecs (gi: 480 thr, gh: 480 thr at 512) ----
        if (tid < 480) {
            gi_s[tid] = gru_gi<480, 24>(wG1IH, fwcout_h, pitch_h, prev_h, pg[0], tid);
        } else if (tid >= 512 && tid < 992) {
            int j = tid - 512;
            gh_s[j] = gru_gh<480, 20>(wG1HH, s1_h, j);
        }
        __syncthreads();

        // ---- G: update s1 || skipin pitch/prev ----
        if (tid < 160) {
            float r = sigm(gi_s[tid] + gh_s[tid]);
            float z = sigm(gi_s[160 + tid] + gh_s[160 + tid]);
            float n = tanh_f(gi_s[320 + tid] + r * gh_s[320 + tid]);
            float v = (1.0f - z) * n + z * s1[tid];
            s1[tid] = v;
            s1_h[tid] = __float2half(v);
        } else if (tid >= 256 && tid < 296) {
            int jj = tid - 256;
            skipin_h[608 + jj] = __float2half(pg[3] * __half2float(pitch_h[jj]));
        } else if (tid >= 296 && tid < 336) {
            skipin_h[648 + tid - 296] = prev_h[tid - 296];
        }
        __syncthreads();

        // ---- H: GLU1 (640 thr, LS=4) ----
        if (tid < 640) {
            float a = mv_red<160, 20, 4>(wGLU1, s1_h, tid);
            if ((tid & 3) == 0) {
                int j = tid >> 2;
                float v = s1[j] * sigm(a);
                __half vh = __float2half(v);
                g1_h[j] = vh;
                skipin_h[j] = vh;
            }
        }
        __syncthreads();

        // ---- J: GRU2 matvecs (gi 384, gh 384) ----
        if (tid < 384) {
            gi_s[tid] = gru_gi<384, 20>(wG2IH, g1_h, pitch_h, prev_h, pg[1], tid);
        } else if (tid < 768) {
            int j = tid - 384;
            gh_s[j] = gru_gh<384, 16>(wG2HH, s2_h, j);
        }
        __syncthreads();

        // ---- K: update s2 ----
        if (tid < 128) {
            float r = sigm(gi_s[tid] + gh_s[tid]);
            float z = sigm(gi_s[128 + tid] + gh_s[128 + tid]);
            float n = tanh_f(gi_s[256 + tid] + r * gh_s[256 + tid]);
            float v = (1.0f - z) * n + z * s2[tid];
            s2[tid] = v;
            s2_h[tid] = __float2half(v);
        }
        __syncthreads();

        // ---- L: GLU2 (1024 thr, LS=8, LDS weights) ----
        {
            float a = mv_red_l<128, 16, 8>(wlds + WL_GLU2, s2_h, tid);
            if ((tid & 7) == 0) {
                int j = tid >> 3;
                float v = s2[j] * sigm(a);
                __half vh = __float2half(v);
                g2_h[j] = vh;
                skipin_h[160 + j] = vh;
            }
        }
        __syncthreads();

        // ---- N: GRU3 matvecs ----
        if (tid < 384) {
            gi_s[tid] = gru_gi<384, 16>(wG3IH, g2_h, pitch_h, prev_h, pg[2], tid);
        } else if (tid < 768) {
            int j = tid - 384;
            gh_s[j] = gru_gh<384, 16>(wG3HH, s3_h, j);
        }
        __syncthreads();

        // ---- O: update s3 ----
        if (tid < 128) {
            float r = sigm(gi_s[tid] + gh_s[tid]);
            float z = sigm(gi_s[128 + tid] + gh_s[128 + tid]);
            float n = tanh_f(gi_s[256 + tid] + r * gh_s[256 + tid]);
            float v = (1.0f - z) * n + z * s3[tid];
            s3[tid] = v;
            s3_h[tid] = __float2half(v);
        }
        __syncthreads();

        // ---- P: GLU3 (1024 thr, LS=8, LDS weights) ----
        {
            float a = mv_red_l<128, 16, 8>(wlds + WL_GLU3, s3_h, tid);
            if ((tid & 7) == 0) {
                int j = tid >> 3;
                skipin_h[288 + j] = __float2half(s3[j] * sigm(a));
            }
        }
        __syncthreads();

        // ---- R: skip (1024 thr, LS=8) ----
        {
            float a = mv_red<128, 88, 8>(wSKIP, skipin_h, tid);
            if ((tid & 7) == 0) {
                int j = tid >> 3;
                float t = tanh_f(a);
                skippre[j] = t;
                skippre_h[j] = __float2half(t);
            }
        }
        __syncthreads();

        // ---- T: skipglu (1024 thr, LS=8) ----
        {
            float a = mv_red<128, 16, 8>(wSKIPGLU, skippre_h, tid);
            if ((tid & 7) == 0) {
                int j = tid >> 3;
                skipout_h[j] = __float2half(skippre[j] * sigm(a));
            }
        }
        __syncthreads();

        // ---- V: sig (320 thr, LS=8) + ring write + output ----
        if (tid < 320) {
            float a = mv_red<40, 16, 8>(wSIG, skipout_h, tid);
            if ((tid & 7) == 0) {
                int j = tid >> 3;
                float sv = tanh_f(a) * gain;
                ring[(head + j) & 255] = sv;     // overwrites 40 oldest (dead)
                out[(size_t)b * 80000 + (size_t)s * 40 + j] = sv;
            }
        }
        __syncthreads();
    }
}

// ---------------------------------------------------------------------------
extern "C" void kernel_launch(void* const* d_in, const int* in_sizes, int n_in,
                              void* d_out, int out_size, void* d_ws, size_t ws_size,
                              hipStream_t stream) {
    const float* features = (const float*)d_in[0];
    const int*   period   = (const int*)d_in[1];
    const float* pembed   = (const float*)d_in[2];
    const float* fd1_w    = (const float*)d_in[3];
    const float* fconv1_w = (const float*)d_in[4];
    const float* fd2_w    = (const float*)d_in[5];
    const float* cg_w     = (const float*)d_in[6];
    const float* cg_b     = (const float*)d_in[7];
    const float* fwc_w    = (const float*)d_in[8];
    const float* fwc_glu  = (const float*)d_in[9];
    const float* g1_ih    = (const float*)d_in[10];
    const float* g1_hh    = (const float*)d_in[11];
    const float* glu1_w   = (const float*)d_in[12];
    const float* g2_ih    = (const float*)d_in[13];
    const float* g2_hh    = (const float*)d_in[14];
    const float* glu2_w   = (const float*)d_in[15];
    const float* g3_ih    = (const float*)d_in[16];
    const float* g3_hh    = (const float*)d_in[17];
    const float* glu3_w   = (const float*)d_in[18];
    const float* skip_w   = (const float*)d_in[19];
    const float* skip_glu = (const float*)d_in[20];
    const float* sig_w    = (const float*)d_in[21];
    const float* gout_w   = (const float*)d_in[22];
    const float* gout_b   = (const float*)d_in[23];

    float* ws = (float*)d_ws;
    float* out = (float*)d_out;
    __half* wh = (__half*)(ws + OFF_W);

    struct PW { const float* src; size_t off; int out, k, kpad; };
    const PW pws[15] = {
        {fwc_w,    W_FWC,     192, 328, 352}, {fwc_glu, W_FWCGLU, 192, 192, 192},
        {gout_w,   W_GOUT,      4, 192, 192}, {g1_ih,   W_G1IH,   480, 272, 272},
        {g1_hh,    W_G1HH,    480, 160, 160}, {glu1_w,  W_GLU1,   160, 160, 160},
        {g2_ih,    W_G2IH,    384, 240, 240}, {g2_hh,   W_G2HH,   384, 128, 128},
        {glu2_w,   W_GLU2,    128, 128, 128}, {g3_ih,   W_G3IH,   384, 208, 208},
        {g3_hh,    W_G3HH,    384, 128, 128}, {glu3_w,  W_GLU3,   128, 128, 128},
        {skip_w,   W_SKIP,    128, 688, 704}, {skip_glu,W_SKIPGLU,128, 128, 128},
        {sig_w,    W_SIG,      40, 128, 128},
    };
    for (int i = 0; i < 15; ++i) {
        int kp8 = pws[i].kpad / 8;
        int n = pws[i].out * kp8;
        k_pack_h<<<(n + 255) / 256, 256, 0, stream>>>(pws[i].src, wh + pws[i].off,
                                                      pws[i].out, pws[i].k, kp8);
    }

    {
        int n = 128 * 502 * 64;
        k_feat<<<(n + 255) / 256, 256, 0, stream>>>(features, period, pembed, fd1_w,
                                                    ws + OFF_X);
    }
    {
        int n = 128 * 500 * 128;
        k_conv<<<(n + 255) / 256, 256, 0, stream>>>(ws + OFF_X, fconv1_w, ws + OFF_Y);
    }
    k_cond<<<128 * 50, 320, 0, stream>>>(ws + OFF_Y, fd2_w, (__half*)(ws + OFF_CONDH));
    {
        int n = 128 * 2000;
        k_gain<<<(n + 255) / 256, 256, 0, stream>>>((const __half*)(ws + OFF_CONDH),
                                                    cg_w, cg_b, ws + OFF_GAIN);
    }

    fargan_main<<<128, 1024, 0, stream>>>(ws, period, gout_b, out);
}

// Round 9
// 49123.511 us; speedup vs baseline: 2.3605x; 2.3605x over previous
//
#include <hip/hip_runtime.h>
#include <hip/hip_fp16.h>
#include <math.h>

// ---------------------------------------------------------------------------
// FARGAN core. B=128, T=504, nb_frames=500, steps=2000, SUB=40.
// Round 9: round-6 streaming plan + in-wave shuffle reductions via INTERLEAVED
// weight repack (lane tid=j*LS+sl reads W[k*OUT*LS + tid] -> coalesced by
// construction; shuffle partners adjacent). GRU matvecs = round-6 gru_partial
// (unchanged, proven). Ring-buffer exc. 16 barriers/step vs 24.
// Round-8 failure root cause: scattered lane mapping broke coalescing
// (FETCH 27MB->85GB, conflicts 1e4->2.8e8). This keeps the mapping sacred.
// ---------------------------------------------------------------------------

#define DEV __device__ __forceinline__

DEV float sigm(float x) { return 1.0f / (1.0f + __expf(-x)); }
DEV float tanh_f(float x) { return 1.0f - 2.0f / (__expf(2.0f * x) + 1.0f); }

typedef _Float16 h2v __attribute__((ext_vector_type(2)));

#if defined(__has_builtin)
#if __has_builtin(__builtin_amdgcn_fdot2)
#define HAVE_FDOT2 1
#endif
#endif

DEV float fdot2(h2v a, h2v b, float c) {
#ifdef HAVE_FDOT2
    return __builtin_amdgcn_fdot2(a, b, c, false);
#else
    return c + (float)a[0] * (float)b[0] + (float)a[1] * (float)b[1];
#endif
}

// ---- workspace layout (float offsets) ----
constexpr size_t STEPS = 2000;
constexpr size_t OFF_X     = 0;          // 128*502*64 f32
constexpr size_t OFF_Y     = 4200000;    // 128*500*128 f32
constexpr size_t OFF_GAIN  = 12392000;   // 128*2000 f32
constexpr size_t OFF_CONDH = 12648000;   // 128*500*320 halves
constexpr size_t OFF_W     = 22888000;   // fp16 weights

// ---- fp16 weight offsets (halves) within OFF_W ----
// Original layout uint4[(k/8)*OUT + j] (GRU mats + gout):
constexpr size_t W_GOUT  = 0;                      // 4   x 192
constexpr size_t W_G1IH  = 768;                    // 480 x 272
constexpr size_t W_G1HH  = W_G1IH + 480*272;       // 480 x 160
constexpr size_t W_G2IH  = W_G1HH + 480*160;       // 384 x 240
constexpr size_t W_G2HH  = W_G2IH + 384*240;       // 384 x 128
constexpr size_t W_G3IH  = W_G2HH + 384*128;       // 384 x 208
constexpr size_t W_G3HH  = W_G3IH + 384*208;       // 384 x 128
// Interleaved layout uint4[k*(OUT*LS) + j*LS + sl], chunk k8 = sl*KS8+k:
constexpr size_t I_FWC     = W_G3HH + 384*128;     // 192 x 352, LS=4
constexpr size_t I_FWCGLU  = I_FWC + 192*352;      // 192 x 192, LS=4 (LDS)
constexpr size_t I_GLU1    = I_FWCGLU + 192*192;   // 160 x 160, LS=4
constexpr size_t I_GLU2    = I_GLU1 + 160*160;     // 128 x 128, LS=8 (LDS)
constexpr size_t I_GLU3    = I_GLU2 + 128*128;     // 128 x 128, LS=8 (LDS)
constexpr size_t I_SKIP    = I_GLU3 + 128*128;     // 128 x 704, LS=8
constexpr size_t I_SKIPGLU = I_SKIP + 128*704;     // 128 x 128, LS=8
constexpr size_t I_SIG     = I_SKIPGLU + 128*128;  // 40  x 128, LS=8

// LDS weight stash offsets (uint4 units) — interleaved, contiguous
constexpr int WL_FWCGLU = 0;       // 24*192 = 4608
constexpr int WL_GLU2   = 4608;    // 2048
constexpr int WL_GLU3   = 6656;    // 2048
constexpr int WL_TOT    = 8704;    // 139,264 B

// ---------------------------------------------------------------------------
// pack fp32 -> fp16, original layout uint4[(k/8)*OUT + j]
__global__ void k_pack_h(const float* __restrict__ src, __half* __restrict__ dst,
                         int OUT, int K, int KP8) {
    int t = blockIdx.x * 256 + threadIdx.x;
    if (t >= OUT * KP8) return;
    int j = t % OUT;
    int k8 = t / OUT;
    __half* d = dst + (size_t)t * 8;
#pragma unroll
    for (int i = 0; i < 8; ++i) {
        int k = k8 * 8 + i;
        d[i] = (k < K) ? __float2half(src[(size_t)j * K + k]) : __float2half(0.0f);
    }
}

// pack fp32 -> fp16, interleaved: dst4[k*(OUT*LS) + j*LS + sl] = row j chunk sl*KS8+k
__global__ void k_pack_i(const float* __restrict__ src, __half* __restrict__ dst,
                         int OUT, int K, int KP8, int LS) {
    int t = blockIdx.x * 256 + threadIdx.x;
    if (t >= OUT * KP8) return;
    int KS8 = KP8 / LS;
    int k = t / (OUT * LS);
    int rem = t % (OUT * LS);
    int j = rem / LS;
    int sl = rem % LS;
    int k8 = sl * KS8 + k;
    __half* d = dst + (size_t)t * 8;
#pragma unroll
    for (int i = 0; i < 8; ++i) {
        int kk = k8 * 8 + i;
        d[i] = (kk < K) ? __float2half(src[(size_t)j * K + kk]) : __float2half(0.0f);
    }
}

// ---------------------------------------------------------------------------
// frontend (unchanged — verified)
// ---------------------------------------------------------------------------
__global__ void k_feat(const float* __restrict__ features, const int* __restrict__ period,
                       const float* __restrict__ pembed, const float* __restrict__ fd1,
                       float* __restrict__ xbuf) {
    int t = blockIdx.x * 256 + threadIdx.x;
    const int total = 128 * 502 * 64;
    if (t >= total) return;
    int o = t & 63;
    int r = t >> 6;
    int ft = r % 502;
    int b = r / 502;
    const float* f = features + ((size_t)b * 504 + ft + 2) * 20;
    int per = period[b * 504 + ft + 2];
    per = min(max(per, 32), 254);
    const float* pe = pembed + (per - 32) * 12;
    const float* w = fd1 + o * 32;
    float acc = 0.0f;
#pragma unroll
    for (int i = 0; i < 20; ++i) acc += f[i] * w[i];
#pragma unroll
    for (int i = 0; i < 12; ++i) acc += pe[i] * w[20 + i];
    xbuf[t] = tanh_f(acc);
}

__global__ void k_conv(const float* __restrict__ xbuf, const float* __restrict__ fconv1,
                       float* __restrict__ ybuf) {
    int t = blockIdx.x * 256 + threadIdx.x;
    const int total = 128 * 500 * 128;
    if (t >= total) return;
    int oc = t & 127;
    int r = t >> 7;
    int tt = r % 500;
    int b = r / 500;
    const float* xp = xbuf + ((size_t)b * 502 + tt) * 64;
    const float* w = fconv1 + oc * 192;
    float acc = 0.0f;
#pragma unroll 8
    for (int i = 0; i < 64; ++i) {
        acc += xp[i] * w[i * 3 + 0];
        acc += xp[64 + i] * w[i * 3 + 1];
        acc += xp[128 + i] * w[i * 3 + 2];
    }
    ybuf[t] = tanh_f(acc);
}

__global__ void k_cond(const float* __restrict__ ybuf, const float* __restrict__ fd2,
                       __half* __restrict__ cond) {
    int b = blockIdx.x / 50;
    int t0 = (blockIdx.x % 50) * 10;
    int tid = threadIdx.x;
    __shared__ float yl[1280];
    for (int i = tid; i < 1280; i += 320)
        yl[i] = ybuf[((size_t)b * 500 + t0) * 128 + i];
    __syncthreads();
    const float* w = fd2 + tid * 128;
    float acc[10];
#pragma unroll
    for (int q = 0; q < 10; ++q) acc[q] = 0.0f;
#pragma unroll 4
    for (int k = 0; k < 128; ++k) {
        float wv = w[k];
#pragma unroll
        for (int q = 0; q < 10; ++q) acc[q] += wv * yl[q * 128 + k];
    }
#pragma unroll
    for (int q = 0; q < 10; ++q)
        cond[((size_t)b * 500 + t0 + q) * 320 + tid] = __float2half(tanh_f(acc[q]));
}

__global__ void k_gain(const __half* __restrict__ cond, const float* __restrict__ cgw,
                       const float* __restrict__ cgb, float* __restrict__ gains) {
    int t = blockIdx.x * 256 + threadIdx.x;
    const int total = 128 * 2000;
    if (t >= total) return;
    int s = t % 2000;
    int b = t / 2000;
    int frame = s >> 2, sub = s & 3;
    const __half* c = cond + ((size_t)b * 500 + frame) * 320 + sub * 80;
    float acc = 0.0f;
#pragma unroll 8
    for (int i = 0; i < 80; ++i) acc += __half2float(c[i]) * cgw[i];
    float g = 0.2f + 0.8f * sigm(acc + cgb[0]);
    g = fminf(20.0f, fmaxf(0.001f, g));
    gains[t] = g;
}

// ---------------------------------------------------------------------------
DEV void dot8h(uint4 w, uint4 x, float& a0, float& a1) {
    const h2v* wv = (const h2v*)&w;
    const h2v* xv = (const h2v*)&x;
    a0 = fdot2(wv[0], xv[0], a0);
    a1 = fdot2(wv[1], xv[1], a1);
    a0 = fdot2(wv[2], xv[2], a0);
    a1 = fdot2(wv[3], xv[3], a1);
}

// interleaved matvec + in-wave reduce. Call with tid < OUT*LS.
// Weight read: W[k*OUT*LS + tid] -> consecutive lanes, consecutive uint4.
template <int OUT, int KS8, int LS>
DEV float mv_red_i(const uint4* __restrict__ W, const __half* __restrict__ x, int tid) {
    const int sl = tid % LS;
    const uint4* w = W + tid;
    const uint4* xx = (const uint4*)x + sl * KS8;
    float a0 = 0.0f, a1 = 0.0f;
#pragma unroll
    for (int k = 0; k < KS8; ++k) dot8h(w[(size_t)k * (OUT * LS)], xx[k], a0, a1);
    float a = a0 + a1;
#pragma unroll
    for (int m = 1; m < LS; m <<= 1) a += __shfl_xor(a, m, 64);
    return a;
}

// same but LDS-resident weights
template <int OUT, int KS8, int LS>
DEV float mv_red_l(const uint4* wl, const __half* __restrict__ x, int tid) {
    const int sl = tid % LS;
    const uint4* w = wl + tid;
    const uint4* xx = (const uint4*)x + sl * KS8;
    float a0 = 0.0f, a1 = 0.0f;
#pragma unroll
    for (int k = 0; k < KS8; ++k) dot8h(w[(size_t)k * (OUT * LS)], xx[k], a0, a1);
    float a = a0 + a1;
#pragma unroll
    for (int m = 1; m < LS; m <<= 1) a += __shfl_xor(a, m, 64);
    return a;
}

// GRU double partial (S=2), original layout, j = tid % OUT (coalesced, proven)
template <int OUT, int KP8A, int KP8B>
DEV void gru_partial(const uint4* __restrict__ wa, const __half* __restrict__ xa,
                     const uint4* __restrict__ wb, const __half* __restrict__ xb,
                     float* __restrict__ pa, float* __restrict__ pb, int tid) {
    constexpr int KA = KP8A / 2, KB = KP8B / 2;
    if (tid < OUT * 2) {
        int j = tid % OUT;
        int sl = tid / OUT;
        {
            const uint4* w = wa + (size_t)sl * KA * OUT + j;
            const uint4* xx = (const uint4*)xa + (size_t)sl * KA;
            float a0 = 0.0f, a1 = 0.0f;
#pragma unroll 4
            for (int k = 0; k < KA; ++k) dot8h(w[(size_t)k * OUT], xx[k], a0, a1);
            pa[tid] = a0 + a1;
        }
        {
            const uint4* w = wb + (size_t)sl * KB * OUT + j;
            const uint4* xx = (const uint4*)xb + (size_t)sl * KB;
            float b0 = 0.0f, b1 = 0.0f;
#pragma unroll 4
            for (int k = 0; k < KB; ++k) dot8h(w[(size_t)k * OUT], xx[k], b0, b1);
            pb[tid] = b0 + b1;
        }
    }
}

template <int H>
DEV void gru_update(const float* __restrict__ pa, const float* __restrict__ pb,
                    float* __restrict__ s, __half* __restrict__ sh, int tid) {
    constexpr int OUT = 3 * H;
    if (tid < H) {
        float gi_r = pa[tid] + pa[OUT + tid];
        float gh_r = pb[tid] + pb[OUT + tid];
        float gi_z = pa[H + tid] + pa[OUT + H + tid];
        float gh_z = pb[H + tid] + pb[OUT + H + tid];
        float gi_n = pa[2 * H + tid] + pa[OUT + 2 * H + tid];
        float gh_n = pb[2 * H + tid] + pb[OUT + 2 * H + tid];
        float r = sigm(gi_r + gh_r);
        float z = sigm(gi_z + gh_z);
        float n = tanh_f(gi_n + r * gh_n);
        float v = (1.0f - z) * n + z * s[tid];
        s[tid] = v;
        sh[tid] = __float2half(v);
    }
}

// ---------------------------------------------------------------------------
// main recurrent kernel: 128 blocks x 1024 threads
// ---------------------------------------------------------------------------
__global__ __launch_bounds__(1024) void fargan_main(const float* __restrict__ ws,
                                                    const int* __restrict__ period,
                                                    const float* __restrict__ goutb,
                                                    float* __restrict__ out) {
    const int b = blockIdx.x;
    const int tid = threadIdx.x;

    const __half* cond = (const __half*)(ws + OFF_CONDH);
    const float* gains = ws + OFF_GAIN;
    const __half* whb  = (const __half*)(ws + OFF_W);
    const uint4* wGOUT   = (const uint4*)(whb + W_GOUT);
    const uint4* wG1IH   = (const uint4*)(whb + W_G1IH);
    const uint4* wG1HH   = (const uint4*)(whb + W_G1HH);
    const uint4* wG2IH   = (const uint4*)(whb + W_G2IH);
    const uint4* wG2HH   = (const uint4*)(whb + W_G2HH);
    const uint4* wG3IH   = (const uint4*)(whb + W_G3IH);
    const uint4* wG3HH   = (const uint4*)(whb + W_G3HH);
    const uint4* iFWC     = (const uint4*)(whb + I_FWC);
    const uint4* iFWCGLU  = (const uint4*)(whb + I_FWCGLU);
    const uint4* iGLU1    = (const uint4*)(whb + I_GLU1);
    const uint4* iGLU2    = (const uint4*)(whb + I_GLU2);
    const uint4* iGLU3    = (const uint4*)(whb + I_GLU3);
    const uint4* iSKIP    = (const uint4*)(whb + I_SKIP);
    const uint4* iSKIPGLU = (const uint4*)(whb + I_SKIPGLU);
    const uint4* iSIG     = (const uint4*)(whb + I_SIG);

    __shared__ __align__(16) uint4 wlds[WL_TOT];

    // fp16 matvec inputs
    __shared__ __align__(16) __half xcat_h[352];   // [state 164|cond 80|pred 44|prev 40|pad]
    __shared__ __align__(16) __half inb_h[272];
    __shared__ __align__(16) __half fwcpre_h[192], fwcout_h[192];
    __shared__ __align__(16) __half s1_h[160], s2_h[128], s3_h[128];
    __shared__ __align__(16) __half skipin_h[704], skippre_h[128], skipout_h[128];
    // fp32 masters
    __shared__ __align__(16) float ring[256];
    __shared__ __align__(16) float s1[160], s2[128], s3[128];
    __shared__ __align__(16) float partA[1024], partB[1024];
    __shared__ __align__(16) float fwcpre[192], skippre[128];
    __shared__ __align__(16) float pg[4];

    // stash LDS weights (interleaved, contiguous copy)
    for (int i = tid; i < 4608; i += 1024) wlds[WL_FWCGLU + i] = iFWCGLU[i];
    for (int i = tid; i < 2048; i += 1024) {
        wlds[WL_GLU2 + i] = iGLU2[i];
        wlds[WL_GLU3 + i] = iGLU3[i];
    }

    // zero-init state
    for (int i = tid; i < 256; i += 1024) ring[i] = 0.0f;
    if (tid < 160) { s1[tid] = 0.0f; s1_h[tid] = __float2half(0.0f); }
    if (tid < 128) { s2[tid] = 0.0f; s3[tid] = 0.0f;
                     s2_h[tid] = __float2half(0.0f); s3_h[tid] = __float2half(0.0f); }
    if (tid < 164) xcat_h[tid] = __float2half(0.0f);
    if (tid >= 328 && tid < 352) xcat_h[tid] = __float2half(0.0f);    // fwc K-pad
    if (tid >= 688 && tid < 704) skipin_h[tid] = __float2half(0.0f);  // skip K-pad
    __syncthreads();

    for (int s = 0; s < (int)STEPS; ++s) {
        const int frame = s >> 2;
        const int head = (s * 40) & 255;
        const float gain = gains[(size_t)b * 2000 + s];
        const float ig = 1.0f / (1e-5f + gain);
        int per = period[b * 504 + 3 + frame];
        per = min(max(per, 32), 254);

        // ---- A: gather cond/pred/prev (ring reads); prev also to skipin ----
        if (tid < 80) {
            xcat_h[164 + tid] = cond[((size_t)b * 500 + frame) * 320 + (s & 3) * 80 + tid];
        } else if (tid >= 128 && tid < 172) {
            int j = tid - 128;
            int idx = 254 - per + j;
            if (idx >= 256) idx -= per;
            idx = min(255, max(0, idx));
            xcat_h[244 + j] = __float2half(ring[(head + idx) & 255] * ig);
        } else if (tid >= 192 && tid < 232) {
            int j = tid - 192;
            __half vh = __float2half(ring[(head + 216 + j) & 255] * ig);
            xcat_h[288 + j] = vh;
            skipin_h[648 + j] = vh;
        }
        __syncthreads();

        // ---- B: fwc in-wave (768 thr, LS=4, KS8=11) ----
        if (tid < 768) {
            float a = mv_red_i<192, 11, 4>(iFWC, xcat_h, tid);
            if ((tid & 3) == 0) {
                int j = tid >> 2;
                float t = tanh_f(a);
                fwcpre[j] = t;
                fwcpre_h[j] = __float2half(t);
            }
        }
        __syncthreads();

        // ---- D: fwcglu (LDS, 768) || gout partial (32) || xcat shift ----
        if (tid < 768) {
            float a = mv_red_l<192, 6, 4>(wlds + WL_FWCGLU, fwcpre_h, tid);
            if ((tid & 3) == 0) {
                int j = tid >> 2;
                float v = fwcpre[j] * sigm(a);
                __half vh = __float2half(v);
                fwcout_h[j] = vh;
                skipin_h[416 + j] = vh;
            }
        } else if (tid < 800) {
            int t2 = tid - 768;
            int j = t2 & 3, sl = t2 >> 2;          // OUT=4, 8 slices x KS8=3 (orig layout)
            const uint4* w = wGOUT + (sl * 3) * 4 + j;
            const uint4* xx = (const uint4*)fwcpre_h + sl * 3;
            float a0 = 0.0f, a1 = 0.0f;
#pragma unroll
            for (int k = 0; k < 3; ++k) dot8h(w[k * 4], xx[k], a0, a1);
            partB[t2] = a0 + a1;
        } else if (tid >= 832 && tid < 996) {
            xcat_h[tid - 832] = xcat_h[tid - 832 + 164];
        }
        __syncthreads();

        // ---- E: pg + inb(gru1) build + skipin pitch(pg3) ----
        if (tid < 192) {
            inb_h[tid] = fwcout_h[tid];
        } else if (tid < 232) {
            float a = goutb[0];
#pragma unroll
            for (int sl = 0; sl < 8; ++sl) a += partB[sl * 4];
            inb_h[tid] = __float2half(sigm(a) * __half2float(xcat_h[246 + tid - 192]));
        } else if (tid < 272) {
            inb_h[tid] = xcat_h[288 + tid - 232];
        } else if (tid >= 288 && tid < 328) {
            float a = goutb[3];
#pragma unroll
            for (int sl = 0; sl < 8; ++sl) a += partB[sl * 4 + 3];
            skipin_h[608 + tid - 288] =
                __float2half(sigm(a) * __half2float(xcat_h[246 + tid - 288]));
        } else if (tid >= 960 && tid < 964) {
            int j = tid - 960;
            float a = goutb[j];
#pragma unroll
            for (int sl = 0; sl < 8; ++sl) a += partB[sl * 4 + j];
            pg[j] = sigm(a);
        }
        __syncthreads();

        // ---- F: GRU1 partial (960 thr) ----
        gru_partial<480, 34, 20>(wG1IH, inb_h, wG1HH, s1_h, partA, partB, tid);
        __syncthreads();
        // ---- G: update s1 + inb(gru2) tail ----
        gru_update<160>(partA, partB, s1, s1_h, tid);
        if (tid >= 192 && tid < 232) {
            inb_h[160 + tid - 192] =
                __float2half(pg[1] * __half2float(xcat_h[246 + tid - 192]));
        } else if (tid >= 232 && tid < 272) {
            inb_h[200 + tid - 232] = xcat_h[288 + tid - 232];
        }
        __syncthreads();

        // ---- H: GLU1 in-wave (640 thr, LS=4, KS8=5) -> g1 into skipin+inb ----
        if (tid < 640) {
            float a = mv_red_i<160, 5, 4>(iGLU1, s1_h, tid);
            if ((tid & 3) == 0) {
                int j = tid >> 2;
                float v = s1[j] * sigm(a);
                __half vh = __float2half(v);
                skipin_h[j] = vh;
                inb_h[j] = vh;
            }
        }
        __syncthreads();

        // ---- J: GRU2 partial (768 thr) ----
        gru_partial<384, 30, 16>(wG2IH, inb_h, wG2HH, s2_h, partA, partB, tid);
        __syncthreads();
        // ---- K: update s2 + inb(gru3) tail ----
        gru_update<128>(partA, partB, s2, s2_h, tid);
        if (tid >= 160 && tid < 200) {
            inb_h[128 + tid - 160] =
                __float2half(pg[2] * __half2float(xcat_h[246 + tid - 160]));
        } else if (tid >= 200 && tid < 240) {
            inb_h[168 + tid - 200] = xcat_h[288 + tid - 200];
        }
        __syncthreads();

        // ---- L: GLU2 in-wave (1024 thr, LS=8, KS8=2, LDS) -> g2 ----
        {
            float a = mv_red_l<128, 2, 8>(wlds + WL_GLU2, s2_h, tid);
            if ((tid & 7) == 0) {
                int j = tid >> 3;
                float v = s2[j] * sigm(a);
                __half vh = __float2half(v);
                skipin_h[160 + j] = vh;
                inb_h[j] = vh;
            }
        }
        __syncthreads();

        // ---- N: GRU3 partial (768 thr) ----
        gru_partial<384, 26, 16>(wG3IH, inb_h, wG3HH, s3_h, partA, partB, tid);
        __syncthreads();
        // ---- O: update s3 ----
        gru_update<128>(partA, partB, s3, s3_h, tid);
        __syncthreads();

        // ---- P: GLU3 in-wave (1024 thr, LS=8, KS8=2, LDS) -> g3 ----
        {
            float a = mv_red_l<128, 2, 8>(wlds + WL_GLU3, s3_h, tid);
            if ((tid & 7) == 0) {
                int j = tid >> 3;
                skipin_h[288 + j] = __float2half(s3[j] * sigm(a));
            }
        }
        __syncthreads();

        // ---- R: skip in-wave (1024 thr, LS=8, KS8=11) ----
        {
            float a = mv_red_i<128, 11, 8>(iSKIP, skipin_h, tid);
            if ((tid & 7) == 0) {
                int j = tid >> 3;
                float t = tanh_f(a);
                skippre[j] = t;
                skippre_h[j] = __float2half(t);
            }
        }
        __syncthreads();

        // ---- T: skipglu in-wave (1024 thr, LS=8, KS8=2) ----
        {
            float a = mv_red_i<128, 2, 8>(iSKIPGLU, skippre_h, tid);
            if ((tid & 7) == 0) {
                int j = tid >> 3;
                skipout_h[j] = __float2half(skippre[j] * sigm(a));
            }
        }
        __syncthreads();

        // ---- V: sig in-wave (320 thr, LS=8, KS8=2) + ring + output ----
        if (tid < 320) {
            float a = mv_red_i<40, 2, 8>(iSIG, skipout_h, tid);
            if ((tid & 7) == 0) {
                int j = tid >> 3;
                float sv = tanh_f(a) * gain;
                ring[(head + j) & 255] = sv;     // overwrites 40 oldest (dead)
                out[(size_t)b * 80000 + (size_t)s * 40 + j] = sv;
            }
        }
        __syncthreads();
    }
}

// ---------------------------------------------------------------------------
extern "C" void kernel_launch(void* const* d_in, const int* in_sizes, int n_in,
                              void* d_out, int out_size, void* d_ws, size_t ws_size,
                              hipStream_t stream) {
    const float* features = (const float*)d_in[0];
    const int*   period   = (const int*)d_in[1];
    const float* pembed   = (const float*)d_in[2];
    const float* fd1_w    = (const float*)d_in[3];
    const float* fconv1_w = (const float*)d_in[4];
    const float* fd2_w    = (const float*)d_in[5];
    const float* cg_w     = (const float*)d_in[6];
    const float* cg_b     = (const float*)d_in[7];
    const float* fwc_w    = (const float*)d_in[8];
    const float* fwc_glu  = (const float*)d_in[9];
    const float* g1_ih    = (const float*)d_in[10];
    const float* g1_hh    = (const float*)d_in[11];
    const float* glu1_w   = (const float*)d_in[12];
    const float* g2_ih    = (const float*)d_in[13];
    const float* g2_hh    = (const float*)d_in[14];
    const float* glu2_w   = (const float*)d_in[15];
    const float* g3_ih    = (const float*)d_in[16];
    const float* g3_hh    = (const float*)d_in[17];
    const float* glu3_w   = (const float*)d_in[18];
    const float* skip_w   = (const float*)d_in[19];
    const float* skip_glu = (const float*)d_in[20];
    const float* sig_w    = (const float*)d_in[21];
    const float* gout_w   = (const float*)d_in[22];
    const float* gout_b   = (const float*)d_in[23];

    float* ws = (float*)d_ws;
    float* out = (float*)d_out;
    __half* wh = (__half*)(ws + OFF_W);

    // original-layout packs (GRU mats + gout)
    struct PW { const float* src; size_t off; int out, k; };
    const PW pws[7] = {
        {gout_w, W_GOUT,   4, 192}, {g1_ih, W_G1IH, 480, 272},
        {g1_hh,  W_G1HH, 480, 160}, {g2_ih, W_G2IH, 384, 240},
        {g2_hh,  W_G2HH, 384, 128}, {g3_ih, W_G3IH, 384, 208},
        {g3_hh,  W_G3HH, 384, 128},
    };
    for (int i = 0; i < 7; ++i) {
        int kp8 = pws[i].k / 8;
        int n = pws[i].out * kp8;
        k_pack_h<<<(n + 255) / 256, 256, 0, stream>>>(pws[i].src, wh + pws[i].off,
                                                      pws[i].out, pws[i].k, kp8);
    }

    // interleaved packs (single-source matvecs)
    struct PI { const float* src; size_t off; int out, k, kpad, ls; };
    const PI pis[8] = {
        {fwc_w,    I_FWC,     192, 328, 352, 4}, {fwc_glu, I_FWCGLU, 192, 192, 192, 4},
        {glu1_w,   I_GLU1,    160, 160, 160, 4}, {glu2_w,  I_GLU2,   128, 128, 128, 8},
        {glu3_w,   I_GLU3,    128, 128, 128, 8}, {skip_w,  I_SKIP,   128, 688, 704, 8},
        {skip_glu, I_SKIPGLU, 128, 128, 128, 8}, {sig_w,   I_SIG,     40, 128, 128, 8},
    };
    for (int i = 0; i < 8; ++i) {
        int kp8 = pis[i].kpad / 8;
        int n = pis[i].out * kp8;
        k_pack_i<<<(n + 255) / 256, 256, 0, stream>>>(pis[i].src, wh + pis[i].off,
                                                      pis[i].out, pis[i].k, kp8,
                                                      pis[i].ls);
    }

    {
        int n = 128 * 502 * 64;
        k_feat<<<(n + 255) / 256, 256, 0, stream>>>(features, period, pembed, fd1_w,
                                                    ws + OFF_X);
    }
    {
        int n = 128 * 500 * 128;
        k_conv<<<(n + 255) / 256, 256, 0, stream>>>(ws + OFF_X, fconv1_w, ws + OFF_Y);
    }
    k_cond<<<128 * 50, 320, 0, stream>>>(ws + OFF_Y, fd2_w, (__half*)(ws + OFF_CONDH));
    {
        int n = 128 * 2000;
        k_gain<<<(n + 255) / 256, 256, 0, stream>>>((const __half*)(ws + OFF_CONDH),
                                                    cg_w, cg_b, ws + OFF_GAIN);
    }

    fargan_main<<<128, 1024, 0, stream>>>(ws, period, gout_b, out);
}